// Round 11
// baseline (218.374 us; speedup 1.0000x reference)
//
#include <hip/hip_runtime.h>
#include <math.h>

#define NDIM 128

// TWO WAVES = ONE BATCH (128-thread blocks, grid = 4096). Lane owns ONE row
// (row = tid) as 64 individually named u32 scalars of packed fp16 (RTN).
// Round-10 lesson: 2 rows/lane (128 u32 + state) overflowed the 128-VGPR
// arch file into AGPRs (VGPR_Count=128, occupancy 19.5%, v_accvgpr traffic,
// latency-bound at VALUBusy 44%). One row/lane needs ~105 VGPRs -> fits the
// 4-waves/SIMD budget (launch_bounds(128,4)), doubling latency hiding AND
// halving every per-lane dependency chain (64 dot2/matvec instead of 128).
// Cost: reductions cross 2 waves -> 2 cheap __syncthreads per CG iter.
//
// Still: Q global read EXACTLY once (round 6: re-reads were HBM-bound);
// no arrays/aggregates/pins (every address-taken form went to scratch);
// broadcast uint4 LDS reads (conflict-free); fp16-RTN Q operator with
// hi/lo (22-bit) x publish for the outer residual u = Qx - r/x.
// Inner: Jacobi-preconditioned Chronopoulos-Gear CG, tol rz<=1e-5*rz0
// (inexact Newton). Outer: exact reference lk/gk logic, exit lk<1e-5.
// absmax measured 1.22e-4 with this numerics stack (threshold 4.17e-4).

typedef __fp16 h2_t __attribute__((ext_vector_type(2)));
union U32H2 { unsigned int u; h2_t h; };

#if __has_builtin(__builtin_amdgcn_fdot2)
#define FDOT2(a,b,c) __builtin_amdgcn_fdot2((a),(b),(c),false)
#else
#define FDOT2(a,b,c) fmaf((float)(a).x,(float)(b).x, fmaf((float)(a).y,(float)(b).y,(c)))
#endif

__device__ __forceinline__ unsigned int pk_rtn(float x, float y) {
    U32H2 r; r.h.x = (__fp16)x; r.h.y = (__fp16)y; return r.u;   // RTN converts
}

#define DOTG(qu, vu, ACC) { U32H2 _q, _v; _q.u = (qu); _v.u = (vu);            \
    ACC = FDOT2(_q.h, _v.h, ACC); }

#define WSUM(v) { v += __shfl_xor(v,32); v += __shfl_xor(v,16);                \
                  v += __shfl_xor(v,8);  v += __shfl_xor(v,4);                 \
                  v += __shfl_xor(v,2);  v += __shfl_xor(v,1); }
#define WMAX(v) { v = fmaxf(v,__shfl_xor(v,32)); v = fmaxf(v,__shfl_xor(v,16));\
                  v = fmaxf(v,__shfl_xor(v,8));  v = fmaxf(v,__shfl_xor(v,4)); \
                  v = fmaxf(v,__shfl_xor(v,2));  v = fmaxf(v,__shfl_xor(v,1)); }

__global__ __launch_bounds__(128, 4)
void rpth_kernel(const float* __restrict__ Q,
                 const float* __restrict__ R,
                 float* __restrict__ out)
{
    const int b    = blockIdx.x;
    const int tid  = threadIdx.x;            // row = tid, 0..127
    const int lane = tid & 63;
    const int wv   = tid >> 6;               // 0..1

    __shared__ __align__(16) unsigned int s_v [64];   // packed CG vector
    __shared__ __align__(16) unsigned int s_xh[64];   // packed x hi
    __shared__ __align__(16) unsigned int s_xl[64];   // packed x lo (x1024)
    __shared__ float s_red[8];

    const size_t qbase = (size_t)b * (NDIM * NDIM);
    const float* prow  = Q + qbase + (size_t)tid * NDIM;

    // ---- 64 named u32 scalars: packed fp16 of this lane's row ----
#define DECL(c) unsigned q##c##_0, q##c##_1, q##c##_2, q##c##_3;
    DECL(0)  DECL(1)  DECL(2)  DECL(3)  DECL(4)  DECL(5)  DECL(6)  DECL(7)
    DECL(8)  DECL(9)  DECL(10) DECL(11) DECL(12) DECL(13) DECL(14) DECL(15)
#undef DECL
#define STG(c) {                                                               \
    const float4 _x0 = ((const float4*)prow)[2*(c)];                           \
    const float4 _x1 = ((const float4*)prow)[2*(c)+1];                         \
    q##c##_0 = pk_rtn(_x0.x,_x0.y); q##c##_1 = pk_rtn(_x0.z,_x0.w);            \
    q##c##_2 = pk_rtn(_x1.x,_x1.y); q##c##_3 = pk_rtn(_x1.z,_x1.w); }
    STG(0)  STG(1)  STG(2)  STG(3)  STG(4)  STG(5)  STG(6)  STG(7)
    STG(8)  STG(9)  STG(10) STG(11) STG(12) STG(13) STG(14) STG(15)
#undef STG

    const float qd = prow[tid];                       // diagonal Q[row][row]
    const float rv = fabsf(R[(size_t)b * NDIM + tid]);

    float xv = rv / sqrtf(qd);               // x0 = r / sqrt(diag Q)
    const float FLc = 0.36286771f;           // 0.95*(3-sqrt(5))/2
    float lk = FLc + 1.0f;

    // publish x as hi/lo fp16 (pairs of adjacent rows; both rows same wave)
#define PUBX() {                                                               \
    const float _hi = (float)(__fp16)xv;                                       \
    const float _lo = (xv - _hi) * 1024.f;                                     \
    const float _xo = __shfl_xor(xv, 1);                                       \
    const float _lo2= __shfl_xor(_lo, 1);                                      \
    if (!(tid & 1)) {                                                          \
        s_xh[tid >> 1] = pk_rtn(xv,  _xo);                                     \
        s_xl[tid >> 1] = pk_rtn(_lo, _lo2);                                    \
    } }
    PUBX();
    __syncthreads();

    const uint4* vhp = (const uint4*)s_xh;
    const uint4* vlp = (const uint4*)s_xl;
    const uint4* vp  = (const uint4*)s_v;

    for (int it = 0; it < 10; ++it) {
        // ---- outer matvec qx = Qh*xh + Qh*xl/1024 (u accurate ~1e-4) ----
        float ah0=0.f, ah1=0.f, al0=0.f, al1=0.f;
#define MVO(c) { const uint4 _Vh = vhp[c], _Vl = vlp[c];                       \
    DOTG(q##c##_0,_Vh.x,ah0) DOTG(q##c##_1,_Vh.y,ah1)                          \
    DOTG(q##c##_2,_Vh.z,ah0) DOTG(q##c##_3,_Vh.w,ah1)                          \
    DOTG(q##c##_0,_Vl.x,al0) DOTG(q##c##_1,_Vl.y,al1)                          \
    DOTG(q##c##_2,_Vl.z,al0) DOTG(q##c##_3,_Vl.w,al1) }
        MVO(0)  MVO(1)  MVO(2)  MVO(3)  MVO(4)  MVO(5)  MVO(6)  MVO(7)
        MVO(8)  MVO(9)  MVO(10) MVO(11) MVO(12) MVO(13) MVO(14) MVO(15)
#undef MVO
        const float qx = fmaf(al0 + al1, 9.765625e-4f, ah0 + ah1);

        const float rx = rv / xv;
        const float u  = qx - rx;                     // u = Qx - r/x
        const float ex = rx / xv;                     // r/x^2
        const float ih = 1.0f / (qd + ex);            // Jacobi precond

        // ---- umax over block -> sigma (fp16 scaling) ----
        float um = fabsf(u);
        WMAX(um);
        if (lane == 0) s_red[4 + wv] = um;
        __syncthreads();
        const float umax  = fmaxf(s_red[4], s_red[5]);
        const float sigma = 1.0f / fmaxf(umax, 1e-30f);

        // ---- Chronopoulos-Gear PCG on h = Qh + diag(ex), scaled RHS ----
        float rs = u * sigma;
        float z  = rs * ih;
        float dk = 0.f, pp = 0.f, sa = 0.f;
        float alpha = 1.f, rzp = 1.f, rz0v = 0.f, invgam = 1.f;
        {
            const float zo = __shfl_xor(z, 1);
            if (!(tid & 1)) s_v[tid >> 1] = pk_rtn(z, zo);
        }
        __syncthreads();

        for (int cg = 0; cg < 16; ++cg) {
            float a0=0.f, a1=0.f, a2=0.f, a3=0.f;
#define MVI(c) { const uint4 _V = vp[c];                                       \
    DOTG(q##c##_0,_V.x,a0) DOTG(q##c##_1,_V.y,a1)                              \
    DOTG(q##c##_2,_V.z,a2) DOTG(q##c##_3,_V.w,a3) }
            MVI(0)  MVI(1)  MVI(2)  MVI(3)  MVI(4)  MVI(5)  MVI(6)  MVI(7)
            MVI(8)  MVI(9)  MVI(10) MVI(11) MVI(12) MVI(13) MVI(14) MVI(15)
#undef MVI
            const float w = fmaf(ex, z, ((a0+a1)+(a2+a3)) * invgam);   // h z

            float pr = rs * z;                        // rz partial
            float pd = z  * w;                        // z.hz partial
            WSUM(pr); WSUM(pd);
            if (lane == 0) { s_red[wv] = pr; s_red[2 + wv] = pd; }
            __syncthreads();
            const float rz    = s_red[0] + s_red[1];
            const float delta = s_red[2] + s_red[3];
            if (cg == 0) { rz0v = rz; if (rz0v <= 1e-30f) break; }
            else if (rz <= 1e-5f * rz0v || rz <= 1e-32f) break;   // loose tol
            const float beta = (cg == 0) ? 0.0f : rz / rzp;
            const float pAp  = delta - beta * rz / alpha;
            alpha = rz / pAp;
            pp = fmaf(beta, pp, z);
            sa = fmaf(beta, sa, w);                   // sa = h p (recurrence)
            dk = fmaf( alpha, pp, dk);
            rs = fmaf(-alpha, sa, rs);
            z  = rs * ih;
            rzp = rz;
            const float gam = rsqrtf(rz);             // republish vhat = z*gam
            invgam = sqrtf(rz);
            {
                const float vhat = z * gam;
                const float vo   = __shfl_xor(vhat, 1);
                if (!(tid & 1)) s_v[tid >> 1] = pk_rtn(vhat, vo);
            }
            __syncthreads();
        }
        const float dku = dk * umax;                  // unscale

        // ---- damping / bookkeeping (exact reference logic, fp32) ----
        float gp = fabsf(dku / xv);
        float sp = dku * u;
        WMAX(gp); WSUM(sp);
        if (lane == 0) { s_red[4 + wv] = gp; s_red[6 + wv] = sp; }
        __syncthreads();
        const float gm  = fmaxf(s_red[4], s_red[5]);
        const float lkk = s_red[6] + s_red[7];
        const float gk     = (lk <= FLc) ? 0.0f : gm;
        const float lk_new = sqrtf(fmaxf(lkk, 0.0f));
        xv = xv - dku / (1.0f + gk);
        lk = lk_new;
        if (lk_new < 1e-5f) break;     // remaining reference motion <= 1e-5
        PUBX();
        __syncthreads();
    }

    // ---- normalize: x / (sum|x| + 1e-8) ----
    float sab = fabsf(xv);
    WSUM(sab);
    if (lane == 0) s_red[wv] = sab;
    __syncthreads();
    const float tot = s_red[0] + s_red[1];
    out[(size_t)b * NDIM + tid] = xv / (tot + 1e-8f);
}

extern "C" void kernel_launch(void* const* d_in, const int* in_sizes, int n_in,
                              void* d_out, int out_size, void* d_ws, size_t ws_size,
                              hipStream_t stream) {
    const float* Q = (const float*)d_in[0];
    const float* R = (const float*)d_in[1];
    float* out     = (float*)d_out;
    const int B    = in_sizes[1] / NDIM;   // 4096
    rpth_kernel<<<dim3(B), dim3(128), 0, stream>>>(Q, R, out);
}